// Round 1
// baseline (336.198 us; speedup 1.0000x reference)
//
#include <hip/hip_runtime.h>
#include <cstdint>
#include <cstddef>

#define F_ALPHA 0.5f
#define THRESH  0.5f
#define EPS8    1e-8f
#define EPS7    1e-7f
#define MAXM    64
#define CCLS    21

// ---------------------------------------------------------------------------
// Kernel 0: init bpkey to key(iou=0, p=0)  -> argmax semantics for all-zero row
// ---------------------------------------------------------------------------
__global__ void init_kernel(unsigned long long* __restrict__ bpkey, int n)
{
    int i = blockIdx.x * 256 + threadIdx.x;
    if (i < n) bpkey[i] = 0x00000000FFFFFFFFull;   // iou bits 0, p = 0
}

// ---------------------------------------------------------------------------
// Kernel A: per-prior best GT (bt) + per-GT best prior (bp) matching.
// bp block-argmax via wave butterfly (shfl_xor max + ballot lowest-lane),
// no LDS staging of the IoU matrix, 2 barriers total.
// grid = (ceil(P/256), B), block = 256.
// ---------------------------------------------------------------------------
__global__ __launch_bounds__(256)
void match_kernel(const float4* __restrict__ dbox,
                  const float4* __restrict__ gt,
                  unsigned long long* __restrict__ bpkey,
                  unsigned char* __restrict__ match,
                  int P, int M)
{
    __shared__ float4 tb[MAXM];
    __shared__ float  tarea[MAXM];
    __shared__ unsigned long long wkey[MAXM][4];

    const int t    = threadIdx.x;
    const int b    = blockIdx.y;
    const int p    = blockIdx.x * 256 + t;
    const bool valid = (p < P);
    const int w    = t >> 6;
    const int lane = t & 63;

    if (t < M) {
        float4 g = gt[(size_t)b * M + t];
        tb[t] = g;
        tarea[t] = (g.z - g.x) * (g.w - g.y);
    }
    __syncthreads();

    // invalid lanes: degenerate box far away -> iou == 0 vs everything
    float4 d = valid ? dbox[p] : make_float4(9.f, 9.f, 9.f, 9.f);
    const float darea = (d.z - d.x) * (d.w - d.y);

    float best = -1.0f;     // bt running max (strict > => first-index tie)
    int   bm = 0;

    const unsigned pbase = blockIdx.x * 256 + (unsigned)(w << 6);

    #pragma unroll 2
    for (int m = 0; m < M; ++m) {
        float4 g = tb[m];
        float ta = tarea[m];
        float lx = fmaxf(d.x, g.x), ly = fmaxf(d.y, g.y);
        float rx = fminf(d.z, g.z), ry = fminf(d.w, g.w);
        float iw = fmaxf(rx - lx, 0.f), ih = fmaxf(ry - ly, 0.f);
        float inter = iw * ih;
        // fast rcp: IoU only feeds compares, 1-ulp error harmless
        float iou = inter * __builtin_amdgcn_rcpf(darea + ta - inter);

        if (iou > best) { best = iou; bm = m; }

        // wave-level max (value only; butterfly keeps all lanes holding vmax)
        float v = iou;
        v = fmaxf(v, __shfl_xor(v,  1, 64));
        v = fmaxf(v, __shfl_xor(v,  2, 64));
        v = fmaxf(v, __shfl_xor(v,  4, 64));
        v = fmaxf(v, __shfl_xor(v,  8, 64));
        v = fmaxf(v, __shfl_xor(v, 16, 64));
        v = fmaxf(v, __shfl_xor(v, 32, 64));

        unsigned long long k;
        if (v > 0.0f) {
            // lowest lane holding the exact max value == lowest prior index
            unsigned long long mb = __ballot(iou == v);
            unsigned wl = (unsigned)(__ffsll((unsigned long long)mb) - 1);
            unsigned pp = pbase + wl;
            k = ((unsigned long long)__float_as_uint(v) << 32)
                | (unsigned long long)(0xFFFFFFFFu - pp);
        } else {
            k = 0x00000000FFFFFFFFull;   // sentinel: iou=0, p=0
        }
        if (lane == 0) wkey[m][w] = k;
    }
    __syncthreads();

    if (t < M) {
        unsigned long long k0 = wkey[t][0], k1 = wkey[t][1];
        unsigned long long k2 = wkey[t][2], k3 = wkey[t][3];
        unsigned long long ka = (k0 > k1) ? k0 : k1;
        unsigned long long kb = (k2 > k3) ? k2 : k3;
        unsigned long long k  = (ka > kb) ? ka : kb;
        // skip atomic when this block saw zero overlap for this GT
        if (k >> 32) atomicMax(&bpkey[(size_t)b * M + t], k);
    }

    if (valid) {
        unsigned char code = (unsigned char)((best >= THRESH ? 0x40 : 0) | bm);
        match[(size_t)b * P + p] = code;
    }
}

// ---------------------------------------------------------------------------
// Kernel B: focal loss on every anchor (conf via coalesced LDS staging) +
// GIoU on positives + fused force-match resolution.
// Per-block partials -> private ws slots (NO contended atomics, no fences).
// ---------------------------------------------------------------------------
__global__ __launch_bounds__(256)
void loss_kernel(const float4* __restrict__ locp,
                 const float*  __restrict__ conf,
                 const float4* __restrict__ dbox,
                 const float4* __restrict__ gt,
                 const int*    __restrict__ gtl,
                 const unsigned long long* __restrict__ bpkey,
                 const unsigned char* __restrict__ match,
                 double* __restrict__ partS,
                 int*    __restrict__ partC,
                 int P, int M)
{
    __shared__ float    scf[256 * CCLS];   // 21504 B conf tile
    __shared__ float4   tb[MAXM];
    __shared__ int      tl[MAXM];
    __shared__ unsigned bpp[MAXM];
    __shared__ double   sv[4];
    __shared__ int      sc[4];

    const int t = threadIdx.x;
    const int b = blockIdx.y;
    const int p0 = blockIdx.x * 256;
    const int p = p0 + t;

    if (t < M) {
        tb[t] = gt[(size_t)b * M + t];
        tl[t] = gtl[(size_t)b * M + t];
        bpp[t] = 0xFFFFFFFFu - (unsigned)(bpkey[(size_t)b * M + t] & 0xFFFFFFFFull);
    }

    // stage conf tile: contiguous [cnt*21] floats, coalesced float4
    const int cnt = min(256, P - p0);
    const int nf = cnt * CCLS;
    const float* src = conf + ((size_t)b * P + p0) * CCLS;
    if (((uintptr_t)src & 15) == 0) {
        const int n4 = nf >> 2;
        const float4* s4 = (const float4*)src;
        float4* d4 = (float4*)scf;
        for (int i = t; i < n4; i += 256) d4[i] = s4[i];
        for (int i = (n4 << 2) + t; i < nf; i += 256) scf[i] = src[i];
    } else {
        for (int i = t; i < nf; i += 256) scf[i] = src[i];
    }
    __syncthreads();

    double acc = 0.0;
    int cnt_pos = 0;
    if (p < P) {
        unsigned char code = match[(size_t)b * P + p];
        int  idx = code & 0x3F;
        bool pos = (code & 0x40) != 0;
        for (int j = 0; j < M; j++) {            // force-match, last-wins
            if (bpp[j] == (unsigned)p) { idx = j; pos = true; }
        }
        int lbl = pos ? tl[idx] : 0;

        // focal loss (precise expf/logf: 1.5M-term sum, bias matters)
        const float* x = scf + t * CCLS;
        float mx = -1e30f;
        #pragma unroll
        for (int c = 0; c < CCLS; c++) mx = fmaxf(mx, x[c]);
        float sum = 0.f;
        #pragma unroll
        for (int c = 0; c < CCLS; c++) sum += expf(x[c] - mx);
        float ce = (mx + logf(sum)) - x[lbl];
        float pt = expf(-ce);
        float om = 1.f - pt;
        acc = (double)(F_ALPHA * om * sqrtf(om) * ce);

        if (pos) {
            cnt_pos = 1;
            float4 d = dbox[p];
            float dw = d.z - d.x, dh = d.w - d.y;
            float dcx = d.x + dw * 0.5f, dcy = d.y + dh * 0.5f;
            float4 g = tb[idx];
            float gw = g.z - g.x, gh = g.w - g.y;
            float gcx = g.x + gw * 0.5f, gcy = g.y + gh * 0.5f;
            float ex = (gcx - dcx) / (dw + EPS8);
            float ey = (gcy - dcy) / (dh + EPS8);
            float ew = logf(gw / (dw + EPS8) + EPS8);
            float eh = logf(gh / (dh + EPS8) + EPS8);
            float tcx = ex * dw + dcx, tcy = ey * dh + dcy;
            float tw = expf(ew) * dw,  th = expf(eh) * dh;
            float t0 = tcx - tw * 0.5f, t1 = tcy - th * 0.5f;
            float t2 = tcx + tw * 0.5f, t3 = tcy + th * 0.5f;
            float4 l = locp[(size_t)b * P + p];
            float pcx = l.x * dw + dcx, pcy = l.y * dh + dcy;
            float pw = expf(l.z) * dw,  ph = expf(l.w) * dh;
            float q0 = pcx - pw * 0.5f, q1 = pcy - ph * 0.5f;
            float q2 = pcx + pw * 0.5f, q3 = pcy + ph * 0.5f;
            float ix0 = fmaxf(q0, t0), iy0 = fmaxf(q1, t1);
            float ix1 = fminf(q2, t2), iy1 = fminf(q3, t3);
            float iw = fmaxf(ix1 - ix0, 0.f), ih = fmaxf(iy1 - iy0, 0.f);
            float inter = iw * ih;
            float pa = (q2 - q0) * (q3 - q1);
            float ta = (t2 - t0) * (t3 - t1);
            float uni = pa + ta - inter;
            float iou = inter / (uni + EPS7);
            float e0 = fminf(q0, t0), e1 = fminf(q1, t1);
            float e2 = fmaxf(q2, t2), e3 = fmaxf(q3, t3);
            float ewd = fmaxf(e2 - e0, 0.f), ehd = fmaxf(e3 - e1, 0.f);
            float encl = ewd * ehd;
            float giou = iou - (encl - uni) / (encl + EPS7);
            acc += (double)(1.f - giou);
        }
    }

    for (int o = 32; o > 0; o >>= 1) {
        acc += __shfl_down(acc, o, 64);
        cnt_pos += __shfl_down(cnt_pos, o, 64);
    }
    int w = t >> 6, lane = t & 63;
    if (lane == 0) { sv[w] = acc; sc[w] = cnt_pos; }
    __syncthreads();
    if (t == 0) {
        int slot = blockIdx.y * gridDim.x + blockIdx.x;
        partS[slot] = sv[0] + sv[1] + sv[2] + sv[3];
        partC[slot] = sc[0] + sc[1] + sc[2] + sc[3];
    }
}

// ---------------------------------------------------------------------------
// Kernel C: reduce per-block partials, divide, write scalar output.
// ---------------------------------------------------------------------------
__global__ __launch_bounds__(256)
void final_kernel(const double* __restrict__ partS,
                  const int*    __restrict__ partC,
                  float* __restrict__ out, int n)
{
    __shared__ double sv[4];
    __shared__ long long sc[4];
    const int t = threadIdx.x;
    double a = 0.0; long long c = 0;
    for (int i = t; i < n; i += 256) { a += partS[i]; c += partC[i]; }
    for (int o = 32; o > 0; o >>= 1) {
        a += __shfl_down(a, o, 64);
        c += __shfl_down(c, o, 64);
    }
    int w = t >> 6, lane = t & 63;
    if (lane == 0) { sv[w] = a; sc[w] = c; }
    __syncthreads();
    if (t == 0) {
        double s = sv[0] + sv[1] + sv[2] + sv[3];
        long long np = sc[0] + sc[1] + sc[2] + sc[3];
        out[0] = (np == 0) ? 0.0f : (float)(s / (double)np);
    }
}

// ---------------------------------------------------------------------------
extern "C" void kernel_launch(void* const* d_in, const int* in_sizes, int n_in,
                              void* d_out, int out_size, void* d_ws, size_t ws_size,
                              hipStream_t stream)
{
    const float* locp = (const float*)d_in[0];   // [B,P,4]
    const float* conf = (const float*)d_in[1];   // [B,P,C]
    const float* dbox = (const float*)d_in[2];   // [P,4]
    const float* gt   = (const float*)d_in[3];   // [B,M,4]
    const int*   gtl  = (const int*)d_in[4];     // [B,M]

    const int P  = in_sizes[2] / 4;
    const long long BP = (long long)in_sizes[0] / 4;
    const int B  = (int)(BP / P);
    const int M  = in_sizes[4] / B;

    const int nblk = (P + 255) / 256;
    const int nPart = nblk * B;

    // ws layout: bpkey[B*M] u64 | partS[nPart] f64 | partC[nPart] i32 | match[B*P] u8
    char* ws = (char*)d_ws;
    unsigned long long* bpkey = (unsigned long long*)ws;
    size_t off = ((size_t)B * M * 8 + 15) & ~(size_t)15;
    double* partS = (double*)(ws + off);
    off += (size_t)nPart * 8;
    int* partC = (int*)(ws + off);
    off += (size_t)nPart * 4;
    off = (off + 15) & ~(size_t)15;
    unsigned char* match = (unsigned char*)(ws + off);

    dim3 grid(nblk, B);
    init_kernel<<<(B * M + 255) / 256, 256, 0, stream>>>(bpkey, B * M);
    match_kernel<<<grid, 256, 0, stream>>>((const float4*)dbox, (const float4*)gt,
                                           bpkey, match, P, M);
    loss_kernel<<<grid, 256, 0, stream>>>((const float4*)locp, conf,
                                          (const float4*)gt /*unused order fix below*/ == nullptr ? (const float4*)dbox : (const float4*)dbox,
                                          (const float4*)gt,
                                          gtl, bpkey, match, partS, partC, P, M);
    final_kernel<<<1, 256, 0, stream>>>(partS, partC, (float*)d_out, nPart);
}

// Round 2
// 301.163 us; speedup vs baseline: 1.1163x; 1.1163x over previous
//
#include <hip/hip_runtime.h>
#include <cstdint>
#include <cstddef>

#define F_ALPHA 0.5f
#define THRESH  0.5f
#define EPS8    1e-8f
#define EPS7    1e-7f
#define MAXM    64
#define CCLS    21
#define GGRP    4      // GTs per bp block

// ---------------------------------------------------------------------------
// Kernel A: per-GT best prior (bp). One block owns GGRP GTs of one image.
// Threads stride P keeping per-GT running (iou,p) max in REGISTERS; the
// cross-lane reduction happens ONCE at the end (u64 key butterfly).
// No atomics, no init kernel. grid = (ceil(M/GGRP), B), block = 256.
// ---------------------------------------------------------------------------
__global__ __launch_bounds__(256)
void bp_kernel(const float4* __restrict__ dbox,
               const float4* __restrict__ gt,
               unsigned* __restrict__ bp,
               int P, int M)
{
    __shared__ unsigned long long wkey[GGRP][4];

    const int b  = blockIdx.y;
    const int m0 = blockIdx.x * GGRP;
    const int t  = threadIdx.x;
    const int w  = t >> 6, lane = t & 63;

    float4 gb[GGRP]; float ga[GGRP];
    #pragma unroll
    for (int g = 0; g < GGRP; g++) {
        int m = min(m0 + g, M - 1);           // pad entries discarded later
        float4 gg = gt[(size_t)b * M + m];
        gb[g] = gg;
        ga[g] = (gg.z - gg.x) * (gg.w - gg.y);
    }

    float    bestv[GGRP];
    unsigned bestp[GGRP];
    #pragma unroll
    for (int g = 0; g < GGRP; g++) { bestv[g] = 0.f; bestp[g] = 0u; }

    for (int p = t; p < P; p += 256) {
        float4 d = dbox[p];
        float darea = (d.z - d.x) * (d.w - d.y);
        #pragma unroll
        for (int g = 0; g < GGRP; g++) {
            float4 gg = gb[g];
            float lx = fmaxf(d.x, gg.x), ly = fmaxf(d.y, gg.y);
            float rx = fminf(d.z, gg.z), ry = fminf(d.w, gg.w);
            float iw = fmaxf(rx - lx, 0.f), ih = fmaxf(ry - ly, 0.f);
            float inter = iw * ih;
            // fast rcp: feeds compares only
            float iou = inter * __builtin_amdgcn_rcpf(darea + ga[g] - inter);
            // strict > : within-thread ties keep lowest p (p increases)
            if (iou > bestv[g]) { bestv[g] = iou; bestp[g] = (unsigned)p; }
        }
    }

    // one-time reduction: key = iou_bits<<32 | ~p  (max => max iou, min p)
    #pragma unroll
    for (int g = 0; g < GGRP; g++) {
        unsigned long long k =
            ((unsigned long long)__float_as_uint(bestv[g]) << 32)
            | (unsigned long long)(0xFFFFFFFFu - bestp[g]);
        #pragma unroll
        for (int o = 1; o < 64; o <<= 1) {
            unsigned long long k2 = __shfl_xor(k, o, 64);
            if (k2 > k) k = k2;
        }
        if (lane == 0) wkey[g][w] = k;
    }
    __syncthreads();
    if (t < GGRP) {
        unsigned long long k0 = wkey[t][0], k1 = wkey[t][1];
        unsigned long long k2 = wkey[t][2], k3 = wkey[t][3];
        unsigned long long ka = (k0 > k1) ? k0 : k1;
        unsigned long long kb = (k2 > k3) ? k2 : k3;
        unsigned long long k  = (ka > kb) ? ka : kb;
        int m = m0 + t;
        if (m < M)
            bp[(size_t)b * M + m] = 0xFFFFFFFFu - (unsigned)(k & 0xFFFFFFFFull);
        // all-zero row: key stays (0, ~0) -> p = 0, matching argmax fallback
    }
}

// ---------------------------------------------------------------------------
// Kernel B: fused bt (per-prior best GT, register-local scan) + force-match
// resolution + focal loss (conf via coalesced LDS staging) + GIoU on
// positives. Per-block partials -> private ws slots.
// ---------------------------------------------------------------------------
__global__ __launch_bounds__(256)
void loss_kernel(const float4* __restrict__ locp,
                 const float*  __restrict__ conf,
                 const float4* __restrict__ dbox,
                 const float4* __restrict__ gt,
                 const int*    __restrict__ gtl,
                 const unsigned* __restrict__ bp,
                 double* __restrict__ partS,
                 int*    __restrict__ partC,
                 int P, int M)
{
    __shared__ float    scf[256 * CCLS];   // 21504 B conf tile
    __shared__ float4   tb[MAXM];
    __shared__ float    tarea[MAXM];
    __shared__ int      tl[MAXM];
    __shared__ unsigned bpp[MAXM];
    __shared__ double   sv[4];
    __shared__ int      sc[4];

    const int t = threadIdx.x;
    const int b = blockIdx.y;
    const int p0 = blockIdx.x * 256;
    const int p = p0 + t;

    if (t < M) {
        float4 g = gt[(size_t)b * M + t];
        tb[t] = g;
        tarea[t] = (g.z - g.x) * (g.w - g.y);
        tl[t] = gtl[(size_t)b * M + t];
        bpp[t] = bp[(size_t)b * M + t];
    }

    // stage conf tile: contiguous [cnt*21] floats, coalesced float4
    const int cnt = min(256, P - p0);
    const int nf = cnt * CCLS;
    const float* src = conf + ((size_t)b * P + p0) * CCLS;
    if (((uintptr_t)src & 15) == 0) {
        const int n4 = nf >> 2;
        const float4* s4 = (const float4*)src;
        float4* d4 = (float4*)scf;
        for (int i = t; i < n4; i += 256) d4[i] = s4[i];
        for (int i = (n4 << 2) + t; i < nf; i += 256) scf[i] = src[i];
    } else {
        for (int i = t; i < nf; i += 256) scf[i] = src[i];
    }
    __syncthreads();

    double acc = 0.0;
    int cnt_pos = 0;
    if (p < P) {
        float4 d = dbox[p];
        const float dw_ = d.z - d.x, dh_ = d.w - d.y;
        const float darea = dw_ * dh_;

        // bt: best GT for this prior (register-local, LDS broadcast reads)
        float best = -1.0f;     // strict > => first-index tie
        int   bm = 0;
        for (int m = 0; m < M; m++) {
            float4 g = tb[m];
            float lx = fmaxf(d.x, g.x), ly = fmaxf(d.y, g.y);
            float rx = fminf(d.z, g.z), ry = fminf(d.w, g.w);
            float iw = fmaxf(rx - lx, 0.f), ih = fmaxf(ry - ly, 0.f);
            float inter = iw * ih;
            float iou = inter * __builtin_amdgcn_rcpf(darea + tarea[m] - inter);
            if (iou > best) { best = iou; bm = m; }
        }

        int  idx = bm;
        bool pos = (best >= THRESH);
        for (int j = 0; j < M; j++) {            // force-match, last-wins
            if (bpp[j] == (unsigned)p) { idx = j; pos = true; }
        }
        int lbl = pos ? tl[idx] : 0;

        // focal loss (precise expf/logf: 1.5M-term sum, bias matters)
        const float* x = scf + t * CCLS;
        float mx = -1e30f;
        #pragma unroll
        for (int c = 0; c < CCLS; c++) mx = fmaxf(mx, x[c]);
        float sum = 0.f;
        #pragma unroll
        for (int c = 0; c < CCLS; c++) sum += expf(x[c] - mx);
        float ce = (mx + logf(sum)) - x[lbl];
        float pt = expf(-ce);
        float om = 1.f - pt;
        acc = (double)(F_ALPHA * om * sqrtf(om) * ce);

        if (pos) {
            cnt_pos = 1;
            float dw = dw_, dh = dh_;
            float dcx = d.x + dw * 0.5f, dcy = d.y + dh * 0.5f;
            float4 g = tb[idx];
            float gw = g.z - g.x, gh = g.w - g.y;
            float gcx = g.x + gw * 0.5f, gcy = g.y + gh * 0.5f;
            float ex = (gcx - dcx) / (dw + EPS8);
            float ey = (gcy - dcy) / (dh + EPS8);
            float ew = logf(gw / (dw + EPS8) + EPS8);
            float eh = logf(gh / (dh + EPS8) + EPS8);
            float tcx = ex * dw + dcx, tcy = ey * dh + dcy;
            float tw = expf(ew) * dw,  th = expf(eh) * dh;
            float t0 = tcx - tw * 0.5f, t1 = tcy - th * 0.5f;
            float t2 = tcx + tw * 0.5f, t3 = tcy + th * 0.5f;
            float4 l = locp[(size_t)b * P + p];
            float pcx = l.x * dw + dcx, pcy = l.y * dh + dcy;
            float pw = expf(l.z) * dw,  ph = expf(l.w) * dh;
            float q0 = pcx - pw * 0.5f, q1 = pcy - ph * 0.5f;
            float q2 = pcx + pw * 0.5f, q3 = pcy + ph * 0.5f;
            float ix0 = fmaxf(q0, t0), iy0 = fmaxf(q1, t1);
            float ix1 = fminf(q2, t2), iy1 = fminf(q3, t3);
            float iw = fmaxf(ix1 - ix0, 0.f), ih = fmaxf(iy1 - iy0, 0.f);
            float inter = iw * ih;
            float pa = (q2 - q0) * (q3 - q1);
            float ta = (t2 - t0) * (t3 - t1);
            float uni = pa + ta - inter;
            float iou = inter / (uni + EPS7);
            float e0 = fminf(q0, t0), e1 = fminf(q1, t1);
            float e2 = fmaxf(q2, t2), e3 = fmaxf(q3, t3);
            float ewd = fmaxf(e2 - e0, 0.f), ehd = fmaxf(e3 - e1, 0.f);
            float encl = ewd * ehd;
            float giou = iou - (encl - uni) / (encl + EPS7);
            acc += (double)(1.f - giou);
        }
    }

    for (int o = 32; o > 0; o >>= 1) {
        acc += __shfl_down(acc, o, 64);
        cnt_pos += __shfl_down(cnt_pos, o, 64);
    }
    int w = t >> 6, lane = t & 63;
    if (lane == 0) { sv[w] = acc; sc[w] = cnt_pos; }
    __syncthreads();
    if (t == 0) {
        int slot = blockIdx.y * gridDim.x + blockIdx.x;
        partS[slot] = sv[0] + sv[1] + sv[2] + sv[3];
        partC[slot] = sc[0] + sc[1] + sc[2] + sc[3];
    }
}

// ---------------------------------------------------------------------------
// Kernel C: reduce per-block partials, divide, write scalar output.
// ---------------------------------------------------------------------------
__global__ __launch_bounds__(256)
void final_kernel(const double* __restrict__ partS,
                  const int*    __restrict__ partC,
                  float* __restrict__ out, int n)
{
    __shared__ double sv[4];
    __shared__ long long sc[4];
    const int t = threadIdx.x;
    double a = 0.0; long long c = 0;
    for (int i = t; i < n; i += 256) { a += partS[i]; c += partC[i]; }
    for (int o = 32; o > 0; o >>= 1) {
        a += __shfl_down(a, o, 64);
        c += __shfl_down(c, o, 64);
    }
    int w = t >> 6, lane = t & 63;
    if (lane == 0) { sv[w] = a; sc[w] = c; }
    __syncthreads();
    if (t == 0) {
        double s = sv[0] + sv[1] + sv[2] + sv[3];
        long long np = sc[0] + sc[1] + sc[2] + sc[3];
        out[0] = (np == 0) ? 0.0f : (float)(s / (double)np);
    }
}

// ---------------------------------------------------------------------------
extern "C" void kernel_launch(void* const* d_in, const int* in_sizes, int n_in,
                              void* d_out, int out_size, void* d_ws, size_t ws_size,
                              hipStream_t stream)
{
    const float* locp = (const float*)d_in[0];   // [B,P,4]
    const float* conf = (const float*)d_in[1];   // [B,P,C]
    const float* dbox = (const float*)d_in[2];   // [P,4]
    const float* gt   = (const float*)d_in[3];   // [B,M,4]
    const int*   gtl  = (const int*)d_in[4];     // [B,M]

    const int P  = in_sizes[2] / 4;
    const long long BP = (long long)in_sizes[0] / 4;
    const int B  = (int)(BP / P);
    const int M  = in_sizes[4] / B;

    const int nblk = (P + 255) / 256;
    const int nPart = nblk * B;

    // ws layout: bp[B*M] u32 | partS[nPart] f64 | partC[nPart] i32
    char* ws = (char*)d_ws;
    unsigned* bp = (unsigned*)ws;
    size_t off = ((size_t)B * M * 4 + 15) & ~(size_t)15;
    double* partS = (double*)(ws + off);
    off += (size_t)nPart * 8;
    int* partC = (int*)(ws + off);

    dim3 gridBP((M + GGRP - 1) / GGRP, B);
    dim3 grid(nblk, B);
    bp_kernel<<<gridBP, 256, 0, stream>>>((const float4*)dbox, (const float4*)gt,
                                          bp, P, M);
    loss_kernel<<<grid, 256, 0, stream>>>((const float4*)locp, conf,
                                          (const float4*)dbox, (const float4*)gt,
                                          gtl, bp, partS, partC, P, M);
    final_kernel<<<1, 256, 0, stream>>>(partS, partC, (float*)d_out, nPart);
}